// Round 6
// baseline (167.045 us; speedup 1.0000x reference)
//
#include <hip/hip_runtime.h>
#include <hip/hip_bf16.h>
#include <math.h>

typedef __bf16 bf16;
typedef __bf16 v8bf __attribute__((ext_vector_type(8)));
typedef __bf16 v4bf __attribute__((ext_vector_type(4)));
typedef float v4f __attribute__((ext_vector_type(4)));

#define N_TOK 2048
#define DIM 1024
#define NH 16
#define FFN_DIM 2816

#define GLL(g, l) __builtin_amdgcn_global_load_lds(                         \
    (const __attribute__((address_space(1))) uint32_t*)(g),                 \
    (__attribute__((address_space(3))) uint32_t*)(l), 16, 0, 0)

#define WAITV(n) do {                                                        \
    switch (n) {                                                             \
    case 0: asm volatile("s_waitcnt vmcnt(0)" ::: "memory"); break;          \
    case 2: asm volatile("s_waitcnt vmcnt(2)" ::: "memory"); break;          \
    case 3: asm volatile("s_waitcnt vmcnt(3)" ::: "memory"); break;          \
    case 4: asm volatile("s_waitcnt vmcnt(4)" ::: "memory"); break;          \
    case 6: asm volatile("s_waitcnt vmcnt(6)" ::: "memory"); break;          \
    case 8: asm volatile("s_waitcnt vmcnt(8)" ::: "memory"); break;          \
    case 9: asm volatile("s_waitcnt vmcnt(9)" ::: "memory"); break;          \
    default: asm volatile("s_waitcnt vmcnt(0)" ::: "memory"); break; }       \
} while (0)

// ---------- all weight transposes+cvt in ONE launch ----------
__global__ __launch_bounds__(256) void transpose_all_kernel(
    const float* __restrict__ w_qkv, const float* __restrict__ w_gate,
    const float* __restrict__ w_out, const float* __restrict__ w_ffng,
    const float* __restrict__ w_ffnu, const float* __restrict__ w_ffnd,
    bf16* __restrict__ wqkvgT, bf16* __restrict__ woutT,
    bf16* __restrict__ wcatT, bf16* __restrict__ wffndT)
{
    int bid = blockIdx.x;
    const float* W; bf16* D; int Kd, Nc, nb, kb, dstbase;
    if (bid < 3072) {
        W = w_qkv; D = wqkvgT; Kd = 1024; Nc = 3072;
        nb = (bid % 96) * 32; kb = (bid / 96) * 32; dstbase = nb;
    } else if (bid < 4096) { int b = bid - 3072;
        W = w_gate; D = wqkvgT; Kd = 1024; Nc = 1024;
        nb = (b % 32) * 32; kb = (b / 32) * 32; dstbase = 3072 + nb;
    } else if (bid < 5120) { int b = bid - 4096;
        W = w_out; D = woutT; Kd = 1024; Nc = 1024;
        nb = (b % 32) * 32; kb = (b / 32) * 32; dstbase = nb;
    } else if (bid < 7936) { int b = bid - 5120;
        W = w_ffng; D = wcatT; Kd = 1024; Nc = 2816;
        nb = (b % 88) * 32; kb = (b / 88) * 32;
        dstbase = (nb >> 6) * 128 + (nb & 63);
    } else if (bid < 10752) { int b = bid - 7936;
        W = w_ffnu; D = wcatT; Kd = 1024; Nc = 2816;
        nb = (b % 88) * 32; kb = (b / 88) * 32;
        dstbase = (nb >> 6) * 128 + 64 + (nb & 63);
    } else { int b = bid - 10752;
        W = w_ffnd; D = wffndT; Kd = 2816; Nc = 1024;
        nb = (b % 32) * 32; kb = (b / 32) * 32; dstbase = nb;
    }
    __shared__ float tile[32][33];
    int tx = threadIdx.x, ty = threadIdx.y;
#pragma unroll
    for (int r = 0; r < 4; ++r)
        tile[ty + r * 8][tx] = W[(size_t)(kb + ty + r * 8) * Nc + nb + tx];
    __syncthreads();
#pragma unroll
    for (int r = 0; r < 4; ++r)
        D[(size_t)(dstbase + ty + r * 8) * Kd + kb + tx] = (bf16)tile[tx][ty + r * 8];
}

// ---------- RMSNorm (f32 in -> bf16 out) ----------
__global__ __launch_bounds__(256) void rmsnorm_kernel(
    const float* __restrict__ x, const float* __restrict__ scale, bf16* __restrict__ out)
{
    int row = blockIdx.x, tid = threadIdx.x;
    float4 v = ((const float4*)(x + (size_t)row * DIM))[tid];
    float ss = v.x * v.x + v.y * v.y + v.z * v.z + v.w * v.w;
#pragma unroll
    for (int off = 32; off > 0; off >>= 1) ss += __shfl_down(ss, off);
    __shared__ float ps[4];
    if ((tid & 63) == 0) ps[tid >> 6] = ss;
    __syncthreads();
    float tot = ps[0] + ps[1] + ps[2] + ps[3];
    float inv = rsqrtf(tot * (1.0f / DIM) + 1e-6f);
    float4 s = ((const float4*)scale)[tid];
    union { bf16 b[4]; uint2 u; } p;
    p.b[0] = (bf16)(v.x * inv * s.x);
    p.b[1] = (bf16)(v.y * inv * s.y);
    p.b[2] = (bf16)(v.z * inv * s.z);
    p.b[3] = (bf16)(v.w * inv * s.w);
    ((uint2*)(out + (size_t)row * DIM))[tid] = p.u;
}

// ---------- gathered-offset attention + gate multiply ----------
// p1: 4-lane group per (offset, head), 2-shfl reduce.
// p2: 16 lanes per head softmax.
// p3: offsets split across 4 waves (11 serial iters), lane owns 16 dims;
//     partials exchanged via LDS, combine fused with gate.
__global__ __launch_bounds__(256) void attn_kernel(
    const bf16* __restrict__ qkvg, const int* __restrict__ offs,
    const float* __restrict__ pos_bias, bf16* __restrict__ attgb)
{
    constexpr int O = 44;
    const int t = blockIdx.x, tid = threadIdx.x;
    const int wv = tid >> 6, lane = tid & 63;
    const int h1 = lane >> 2, l4 = lane & 3;
    const size_t RS = 4 * DIM;
    __shared__ float sS[O][17];
    __shared__ float sPB[O * 16];
    __shared__ int so[O];
    __shared__ float sAcc[4 * 1024];
    if (tid < O) so[tid] = offs[tid];
    for (int i = tid; i < O * 16; i += 256) sPB[i] = pos_bias[i];
    __syncthreads();

    // ----- phase 1: scores -----
    const bf16* qbase = qkvg + (size_t)t * RS + h1 * 64;
    v8bf q0v = *(const v8bf*)(qbase + l4 * 8);
    v8bf q1v = *(const v8bf*)(qbase + 32 + l4 * 8);
    float qa[16];
#pragma unroll
    for (int e = 0; e < 8; ++e) {
        qa[e] = (float)q0v[e] * 0.125f;
        qa[8 + e] = (float)q1v[e] * 0.125f;
    }

#pragma unroll 4
    for (int it = 0; it < 11; ++it) {
        const int o = it * 4 + wv;
        const int src = t - so[o];
        const int srcc = src < 0 ? 0 : src;
        const bf16* kbase = qkvg + (size_t)srcc * RS + DIM + h1 * 64;
        v8bf k0 = *(const v8bf*)(kbase + l4 * 8);
        v8bf k1 = *(const v8bf*)(kbase + 32 + l4 * 8);
        float p = 0.f;
#pragma unroll
        for (int e = 0; e < 8; ++e) p += qa[e] * (float)k0[e];
#pragma unroll
        for (int e = 0; e < 8; ++e) p += qa[8 + e] * (float)k1[e];
        p += __shfl_xor(p, 1);
        p += __shfl_xor(p, 2);
        float s = (src >= 0) ? p + sPB[o * NH + h1] : -INFINITY;
        if (l4 == 0) sS[o][h1] = s;
    }
    __syncthreads();

    // ----- phase 2: per-head softmax stats -----
    const int h = tid >> 4, j16 = tid & 15;
    float mx = -INFINITY;
#pragma unroll
    for (int o = j16; o < O; o += 16) mx = fmaxf(mx, sS[o][h]);
    mx = fmaxf(mx, __shfl_xor(mx, 1));
    mx = fmaxf(mx, __shfl_xor(mx, 2));
    mx = fmaxf(mx, __shfl_xor(mx, 4));
    mx = fmaxf(mx, __shfl_xor(mx, 8));
    float sum = 0.f;
#pragma unroll
    for (int o = j16; o < O; o += 16) {
        float e = __expf(sS[o][h] - mx);
        sS[o][h] = e;
        sum += e;
    }
    sum += __shfl_xor(sum, 1);
    sum += __shfl_xor(sum, 2);
    sum += __shfl_xor(sum, 4);
    sum += __shfl_xor(sum, 8);
    float inv = 1.0f / sum;
    __syncthreads();

    // ----- phase 3: PV, offsets split across waves; lane owns 16 dims -----
    const int h2 = lane >> 2;
    const int dbase = lane * 16;
    float pacc[16] = {};
#pragma unroll 4
    for (int it = 0; it < 11; ++it) {
        int o = it * 4 + wv;
        int src = t - so[o];
        int srcc = src < 0 ? 0 : src;
        float a = sS[o][h2];         // 0 for invalid offsets
        const bf16* vb = qkvg + (size_t)srcc * RS + 2 * DIM + dbase;
        v8bf v0 = *(const v8bf*)(vb);
        v8bf v1 = *(const v8bf*)(vb + 8);
#pragma unroll
        for (int e = 0; e < 8; ++e) {
            pacc[e] += a * (float)v0[e];
            pacc[8 + e] += a * (float)v1[e];
        }
    }
    // write partials (swizzled float4 chunks)
#pragma unroll
    for (int q = 0; q < 4; ++q) {
        int phys = lane * 4 + (q ^ (lane & 3));
        *(float4*)&sAcc[wv * 1024 + phys * 4] =
            make_float4(pacc[q * 4], pacc[q * 4 + 1], pacc[q * 4 + 2], pacc[q * 4 + 3]);
    }
    __syncthreads();

    // ----- combine + gate: thread owns dims [tid*4, tid*4+4) -----
    const int lr = tid >> 2, qr = tid & 3;
    const int phys = lr * 4 + (qr ^ (lr & 3));
    float4 p0 = *(const float4*)&sAcc[0 * 1024 + phys * 4];
    float4 p1 = *(const float4*)&sAcc[1 * 1024 + phys * 4];
    float4 p2 = *(const float4*)&sAcc[2 * 1024 + phys * 4];
    float4 p3 = *(const float4*)&sAcc[3 * 1024 + phys * 4];
    v4bf gv = *(const v4bf*)(qkvg + (size_t)t * RS + 3 * DIM + tid * 4);
    v4bf ov;
    ov[0] = (bf16)((p0.x + p1.x + p2.x + p3.x) * inv * (float)gv[0]);
    ov[1] = (bf16)((p0.y + p1.y + p2.y + p3.y) * inv * (float)gv[1]);
    ov[2] = (bf16)((p0.z + p1.z + p2.z + p3.z) * inv * (float)gv[2]);
    ov[3] = (bf16)((p0.w + p1.w + p2.w + p3.w) * inv * (float)gv[3]);
    *(v4bf*)(attgb + (size_t)t * DIM + tid * 4) = ov;
}

// ---------- bf16 MFMA GEMM, NBUF-deep pipeline, counted vmcnt, XOR-swizzled LDS ----------
// EPI: 3 = residual f32 (outf = e1 + acc)
//      5 = qkv+gate (col<3072: bf16 acc; else bf16 sigmoid(acc+bias[col-3072]))
//      6 = interleaved ffn gate/up: outb = silu(gate)*up via LDS exchange
template<int BM, int BN, int NTHR, int NBUF, int EPI>
__global__ __launch_bounds__(NTHR) void gemm_kernel(
    const bf16* __restrict__ A, const bf16* __restrict__ Bt,
    int M, int N, int K,
    float* __restrict__ outf, bf16* __restrict__ outb,
    const float* __restrict__ e1, const float* __restrict__ bias)
{
    constexpr int WAVES = NTHR / 64;
    constexpr int WCOLS = WAVES / 2;
    constexpr int WME = BM / 2;
    constexpr int WNE = BN / WCOLS;
    constexpr int MI = WME / 16;
    constexpr int NJ = WNE / 16;
    constexpr int CH_A = BM * 4, CH_B = BN * 4;
    constexpr int LPT = (CH_A + CH_B) / NTHR;
    constexpr int STAGE_BYTES = NBUF * (BM + BN) * 32 * 2;
    constexpr int EPI_BYTES = (EPI == 6) ? BM * 66 * 4 : 0;
    constexpr int SMEM_BYTES = STAGE_BYTES > EPI_BYTES ? STAGE_BYTES : EPI_BYTES;
    __shared__ __align__(16) char smem[SMEM_BYTES];
    bf16* AsB = (bf16*)smem;                              // [NBUF][BM*32]
    bf16* BsB = (bf16*)(smem + NBUF * BM * 32 * 2);       // [NBUF][BN*32]

    const int tid = threadIdx.x;
    const int m0 = blockIdx.y * BM, n0 = blockIdx.x * BN;
    const int lane = tid & 63, wave = tid >> 6;
    const int wr = wave / WCOLS, wc = wave % WCOLS;
    const int wm = wr * WME, wn = wc * WNE;
    const int lrow = lane & 15, l16 = lane >> 4;

    // staging: chunk c = tid + i*NTHR; A chunks first, then B; global col pre-swizzled
    const bf16* gptr[LPT];
    int lo[LPT];
    bool pa[LPT];
#pragma unroll
    for (int i = 0; i < LPT; ++i) {
        int c = tid + i * NTHR;
        bool inA = c < CH_A;
        int cc = inA ? c : c - CH_A;
        int r = cc >> 2, q = cc & 3;
        int gq = (q ^ ((r >> 1) & 3)) * 8;
        gptr[i] = inA ? A + (size_t)(m0 + r) * K + gq
                      : Bt + (size_t)(n0 + r) * K + gq;
        lo[i] = r * 32 + q * 8;
        pa[i] = inA;
    }

    auto STAGE = [&](int b, int kt) {
        const int ko = kt * 32;
#pragma unroll
        for (int i = 0; i < LPT; ++i) {
            bf16* dst = (pa[i] ? AsB + b * BM * 32 : BsB + b * BN * 32) + lo[i];
            GLL(gptr[i] + ko, dst);
        }
    };

    v4f acc[MI][NJ] = {};
    auto COMPUTE = [&](int b) {
        v8bf af[MI], bfr[NJ];
#pragma unroll
        for (int i = 0; i < MI; ++i) {
            int r = wm + i * 16 + lrow;
            af[i] = *(v8bf*)&AsB[b * BM * 32 + r * 32 + ((l16 ^ ((r >> 1) & 3)) * 8)];
        }
#pragma unroll
        for (int j = 0; j < NJ; ++j) {
            int r = wn + j * 16 + lrow;
            bfr[j] = *(v8bf*)&BsB[b * BN * 32 + r * 32 + ((l16 ^ ((r >> 1) & 3)) * 8)];
        }
        __builtin_amdgcn_s_setprio(1);
#pragma unroll
        for (int i = 0; i < MI; ++i)
#pragma unroll
            for (int j = 0; j < NJ; ++j)
                acc[i][j] = __builtin_amdgcn_mfma_f32_16x16x32_bf16(af[i], bfr[j], acc[i][j], 0, 0, 0);
        __builtin_amdgcn_s_setprio(0);
    };

    const int NT = K >> 5;
#pragma unroll
    for (int i = 0; i < NBUF; ++i) STAGE(i, i);
    for (int t = 0; t < NT - (NBUF - 1); ++t) {
        WAITV((NBUF - 1) * LPT);
        __builtin_amdgcn_s_barrier();
        __builtin_amdgcn_sched_barrier(0);
        COMPUTE(t & (NBUF - 1));
        __builtin_amdgcn_sched_barrier(0);
        __builtin_amdgcn_s_barrier();
        if (t + NBUF < NT) STAGE(t & (NBUF - 1), t + NBUF);
    }
#pragma unroll
    for (int e = NBUF - 1; e >= 1; --e) {
        const int t = NT - e;
        WAITV((e - 1) * LPT);
        __builtin_amdgcn_s_barrier();
        __builtin_amdgcn_sched_barrier(0);
        COMPUTE(t & (NBUF - 1));
        __builtin_amdgcn_sched_barrier(0);
        __builtin_amdgcn_s_barrier();
    }

    if constexpr (EPI == 6) {
        float* eps = (float*)smem;
        const bool isGate = (wn < 64);
        if (isGate) {
#pragma unroll
            for (int i = 0; i < MI; ++i)
#pragma unroll
                for (int j = 0; j < NJ; ++j)
#pragma unroll
                    for (int r = 0; r < 4; ++r) {
                        int rowL = wm + i * 16 + l16 * 4 + r;
                        int colL = wn + j * 16 + lrow;
                        eps[rowL * 66 + colL] = acc[i][j][r];
                    }
        }
        asm volatile("s_waitcnt lgkmcnt(0)" ::: "memory");
        __builtin_amdgcn_s_barrier();
        if (!isGate) {
            const int halfN = N >> 1;
#pragma unroll
            for (int i = 0; i < MI; ++i)
#pragma unroll
                for (int j = 0; j < NJ; ++j)
#pragma unroll
                    for (int r = 0; r < 4; ++r) {
                        int rowL = wm + i * 16 + l16 * 4 + r;
                        int colU = wn - 64 + j * 16 + lrow;
                        float g = eps[rowL * 66 + colU];
                        float sil = g / (1.0f + __expf(-g));
                        float u = acc[i][j][r];
                        outb[(size_t)(m0 + rowL) * halfN + (n0 >> 1) + colU] = (bf16)(sil * u);
                    }
        }
        return;
    }

#pragma unroll
    for (int i = 0; i < MI; ++i)
#pragma unroll
        for (int j = 0; j < NJ; ++j)
#pragma unroll
            for (int r = 0; r < 4; ++r) {
                int row = m0 + wm + i * 16 + l16 * 4 + r;
                int col = n0 + wn + j * 16 + lrow;
                size_t idx = (size_t)row * N + col;
                float v = acc[i][j][r];
                if constexpr (EPI == 3) {
                    outf[idx] = e1[idx] + v;
                } else if constexpr (EPI == 5) {
                    if (col >= 3 * DIM) {
                        float g = 1.0f / (1.0f + __expf(-(v + bias[col - 3 * DIM])));
                        outb[idx] = (bf16)g;
                    } else {
                        outb[idx] = (bf16)v;
                    }
                }
            }
}

extern "C" void kernel_launch(void* const* d_in, const int* in_sizes, int n_in,
                              void* d_out, int out_size, void* d_ws, size_t ws_size,
                              hipStream_t stream)
{
    const float* x        = (const float*)d_in[0];
    const float* n1s      = (const float*)d_in[1];
    const float* n2s      = (const float*)d_in[2];
    const float* w_qkv    = (const float*)d_in[3];
    const float* w_out    = (const float*)d_in[4];
    const float* w_gate   = (const float*)d_in[5];
    const float* b_gate   = (const float*)d_in[6];
    const float* pos_bias = (const float*)d_in[7];
    const float* w_ffng   = (const float*)d_in[8];
    const float* w_ffnu   = (const float*)d_in[9];
    const float* w_ffnd   = (const float*)d_in[10];
    const int* offsets    = (const int*)d_in[11];
    float* out = (float*)d_out;

    char* ws = (char*)d_ws;
    size_t cur = 0;
    auto alloc = [&](size_t bytes) -> void* {
        void* p = ws + cur;
        cur += (bytes + 255) & ~(size_t)255;
        return p;
    };
    bf16*  xnb    = (bf16*)alloc((size_t)N_TOK * DIM * 2);
    bf16*  qkvgb  = (bf16*)alloc((size_t)N_TOK * 4 * DIM * 2);
    bf16*  attgb  = (bf16*)alloc((size_t)N_TOK * DIM * 2);
    float* x1     = (float*)alloc((size_t)N_TOK * DIM * 4);
    bf16*  xn2b   = (bf16*)alloc((size_t)N_TOK * DIM * 2);
    bf16*  hb     = (bf16*)alloc((size_t)N_TOK * FFN_DIM * 2);
    bf16*  wqkvgT = (bf16*)alloc((size_t)4 * DIM * DIM * 2);
    bf16*  woutT  = (bf16*)alloc((size_t)DIM * DIM * 2);
    bf16*  wcatT  = (bf16*)alloc((size_t)2 * FFN_DIM * DIM * 2);
    bf16*  wffndT = (bf16*)alloc((size_t)FFN_DIM * DIM * 2);

    transpose_all_kernel<<<13568, dim3(32, 8), 0, stream>>>(
        w_qkv, w_gate, w_out, w_ffng, w_ffnu, w_ffnd,
        wqkvgT, woutT, wcatT, wffndT);

    rmsnorm_kernel<<<N_TOK, 256, 0, stream>>>(x, n1s, xnb);
    // fused qkv + gate: N=4096, 64x128 tiles -> 1024 blocks
    gemm_kernel<64, 128, 256, 2, 5><<<dim3(32, 32), 256, 0, stream>>>(
        xnb, wqkvgT, N_TOK, 4 * DIM, DIM, nullptr, qkvgb, nullptr, b_gate);
    attn_kernel<<<dim3(N_TOK), 256, 0, stream>>>(qkvgb, offsets, pos_bias, attgb);
    // x1 = x + attg @ w_out  (64x64, NBUF=4)
    gemm_kernel<64, 64, 256, 4, 3><<<dim3(16, 32), 256, 0, stream>>>(
        attgb, woutT, N_TOK, DIM, DIM, x1, nullptr, x, nullptr);
    rmsnorm_kernel<<<N_TOK, 256, 0, stream>>>(x1, n2s, xn2b);
    // fused ffn gate|up interleaved: N=5632, 64x128 tiles -> 1408 blocks
    gemm_kernel<64, 128, 256, 2, 6><<<dim3(44, 32), 256, 0, stream>>>(
        xn2b, wcatT, N_TOK, 2 * FFN_DIM, DIM, nullptr, hb, nullptr, nullptr);
    // out = x1 + hb @ w_ffn_down  (64x64, K=2816, NBUF=4)
    gemm_kernel<64, 64, 256, 4, 3><<<dim3(16, 32), 256, 0, stream>>>(
        hb, wffndT, N_TOK, DIM, FFN_DIM, out, nullptr, x1, nullptr);
}

// Round 7
// 157.096 us; speedup vs baseline: 1.0633x; 1.0633x over previous
//
#include <hip/hip_runtime.h>
#include <hip/hip_bf16.h>
#include <math.h>

typedef __bf16 bf16;
typedef __bf16 v8bf __attribute__((ext_vector_type(8)));
typedef __bf16 v4bf __attribute__((ext_vector_type(4)));
typedef float v4f __attribute__((ext_vector_type(4)));

#define N_TOK 2048
#define DIM 1024
#define NH 16
#define FFN_DIM 2816

#define GLL(g, l) __builtin_amdgcn_global_load_lds(                         \
    (const __attribute__((address_space(1))) uint32_t*)(g),                 \
    (__attribute__((address_space(3))) uint32_t*)(l), 16, 0, 0)

#define WAITV(n) do {                                                        \
    switch (n) {                                                             \
    case 0: asm volatile("s_waitcnt vmcnt(0)" ::: "memory"); break;          \
    case 2: asm volatile("s_waitcnt vmcnt(2)" ::: "memory"); break;          \
    case 3: asm volatile("s_waitcnt vmcnt(3)" ::: "memory"); break;          \
    case 4: asm volatile("s_waitcnt vmcnt(4)" ::: "memory"); break;          \
    case 6: asm volatile("s_waitcnt vmcnt(6)" ::: "memory"); break;          \
    case 8: asm volatile("s_waitcnt vmcnt(8)" ::: "memory"); break;          \
    case 9: asm volatile("s_waitcnt vmcnt(9)" ::: "memory"); break;          \
    default: asm volatile("s_waitcnt vmcnt(0)" ::: "memory"); break; }       \
} while (0)

// ---------- all weight transposes+cvt in ONE launch ----------
__global__ __launch_bounds__(256) void transpose_all_kernel(
    const float* __restrict__ w_qkv, const float* __restrict__ w_gate,
    const float* __restrict__ w_out, const float* __restrict__ w_ffng,
    const float* __restrict__ w_ffnu, const float* __restrict__ w_ffnd,
    bf16* __restrict__ wqkvgT, bf16* __restrict__ woutT,
    bf16* __restrict__ wcatT, bf16* __restrict__ wffndT)
{
    int bid = blockIdx.x;
    const float* W; bf16* D; int Kd, Nc, nb, kb, dstbase;
    if (bid < 3072) {
        W = w_qkv; D = wqkvgT; Kd = 1024; Nc = 3072;
        nb = (bid % 96) * 32; kb = (bid / 96) * 32; dstbase = nb;
    } else if (bid < 4096) { int b = bid - 3072;
        W = w_gate; D = wqkvgT; Kd = 1024; Nc = 1024;
        nb = (b % 32) * 32; kb = (b / 32) * 32; dstbase = 3072 + nb;
    } else if (bid < 5120) { int b = bid - 4096;
        W = w_out; D = woutT; Kd = 1024; Nc = 1024;
        nb = (b % 32) * 32; kb = (b / 32) * 32; dstbase = nb;
    } else if (bid < 7936) { int b = bid - 5120;
        W = w_ffng; D = wcatT; Kd = 1024; Nc = 2816;
        nb = (b % 88) * 32; kb = (b / 88) * 32;
        dstbase = (nb >> 6) * 128 + (nb & 63);
    } else if (bid < 10752) { int b = bid - 7936;
        W = w_ffnu; D = wcatT; Kd = 1024; Nc = 2816;
        nb = (b % 88) * 32; kb = (b / 88) * 32;
        dstbase = (nb >> 6) * 128 + 64 + (nb & 63);
    } else { int b = bid - 10752;
        W = w_ffnd; D = wffndT; Kd = 2816; Nc = 1024;
        nb = (b % 32) * 32; kb = (b / 32) * 32; dstbase = nb;
    }
    __shared__ float tile[32][33];
    int tx = threadIdx.x, ty = threadIdx.y;
#pragma unroll
    for (int r = 0; r < 4; ++r)
        tile[ty + r * 8][tx] = W[(size_t)(kb + ty + r * 8) * Nc + nb + tx];
    __syncthreads();
#pragma unroll
    for (int r = 0; r < 4; ++r)
        D[(size_t)(dstbase + ty + r * 8) * Kd + kb + tx] = (bf16)tile[tx][ty + r * 8];
}

// ---------- RMSNorm (f32 in -> bf16 out) ----------
__global__ __launch_bounds__(256) void rmsnorm_kernel(
    const float* __restrict__ x, const float* __restrict__ scale, bf16* __restrict__ out)
{
    int row = blockIdx.x, tid = threadIdx.x;
    float4 v = ((const float4*)(x + (size_t)row * DIM))[tid];
    float ss = v.x * v.x + v.y * v.y + v.z * v.z + v.w * v.w;
#pragma unroll
    for (int off = 32; off > 0; off >>= 1) ss += __shfl_down(ss, off);
    __shared__ float ps[4];
    if ((tid & 63) == 0) ps[tid >> 6] = ss;
    __syncthreads();
    float tot = ps[0] + ps[1] + ps[2] + ps[3];
    float inv = rsqrtf(tot * (1.0f / DIM) + 1e-6f);
    float4 s = ((const float4*)scale)[tid];
    union { bf16 b[4]; uint2 u; } p;
    p.b[0] = (bf16)(v.x * inv * s.x);
    p.b[1] = (bf16)(v.y * inv * s.y);
    p.b[2] = (bf16)(v.z * inv * s.z);
    p.b[3] = (bf16)(v.w * inv * s.w);
    ((uint2*)(out + (size_t)row * DIM))[tid] = p.u;
}

// ---------- gathered-offset attention + gate multiply ----------
__global__ __launch_bounds__(256) void attn_kernel(
    const bf16* __restrict__ qkvg, const int* __restrict__ offs,
    const float* __restrict__ pos_bias, bf16* __restrict__ attgb)
{
    constexpr int O = 44;
    const int t = blockIdx.x, tid = threadIdx.x;
    const int wv = tid >> 6, lane = tid & 63;
    const int h1 = lane >> 2, l4 = lane & 3;
    const size_t RS = 4 * DIM;
    __shared__ float sS[O][17];
    __shared__ float sPB[O * 16];
    __shared__ int so[O];
    __shared__ float sAcc[4 * 1024];
    if (tid < O) so[tid] = offs[tid];
    for (int i = tid; i < O * 16; i += 256) sPB[i] = pos_bias[i];
    __syncthreads();

    // ----- phase 1: scores -----
    const bf16* qbase = qkvg + (size_t)t * RS + h1 * 64;
    v8bf q0v = *(const v8bf*)(qbase + l4 * 8);
    v8bf q1v = *(const v8bf*)(qbase + 32 + l4 * 8);
    float qa[16];
#pragma unroll
    for (int e = 0; e < 8; ++e) {
        qa[e] = (float)q0v[e] * 0.125f;
        qa[8 + e] = (float)q1v[e] * 0.125f;
    }

#pragma unroll 4
    for (int it = 0; it < 11; ++it) {
        const int o = it * 4 + wv;
        const int src = t - so[o];
        const int srcc = src < 0 ? 0 : src;
        const bf16* kbase = qkvg + (size_t)srcc * RS + DIM + h1 * 64;
        v8bf k0 = *(const v8bf*)(kbase + l4 * 8);
        v8bf k1 = *(const v8bf*)(kbase + 32 + l4 * 8);
        float p = 0.f;
#pragma unroll
        for (int e = 0; e < 8; ++e) p += qa[e] * (float)k0[e];
#pragma unroll
        for (int e = 0; e < 8; ++e) p += qa[8 + e] * (float)k1[e];
        p += __shfl_xor(p, 1);
        p += __shfl_xor(p, 2);
        float s = (src >= 0) ? p + sPB[o * NH + h1] : -INFINITY;
        if (l4 == 0) sS[o][h1] = s;
    }
    __syncthreads();

    // ----- phase 2: per-head softmax stats -----
    const int h = tid >> 4, j16 = tid & 15;
    float mx = -INFINITY;
#pragma unroll
    for (int o = j16; o < O; o += 16) mx = fmaxf(mx, sS[o][h]);
    mx = fmaxf(mx, __shfl_xor(mx, 1));
    mx = fmaxf(mx, __shfl_xor(mx, 2));
    mx = fmaxf(mx, __shfl_xor(mx, 4));
    mx = fmaxf(mx, __shfl_xor(mx, 8));
    float sum = 0.f;
#pragma unroll
    for (int o = j16; o < O; o += 16) {
        float e = __expf(sS[o][h] - mx);
        sS[o][h] = e;
        sum += e;
    }
    sum += __shfl_xor(sum, 1);
    sum += __shfl_xor(sum, 2);
    sum += __shfl_xor(sum, 4);
    sum += __shfl_xor(sum, 8);
    float inv = 1.0f / sum;
    __syncthreads();

    // ----- phase 3: PV, offsets split across waves; lane owns 16 dims -----
    const int h2 = lane >> 2;
    const int dbase = lane * 16;
    float pacc[16] = {};
#pragma unroll 4
    for (int it = 0; it < 11; ++it) {
        int o = it * 4 + wv;
        int src = t - so[o];
        int srcc = src < 0 ? 0 : src;
        float a = sS[o][h2];
        const bf16* vb = qkvg + (size_t)srcc * RS + 2 * DIM + dbase;
        v8bf v0 = *(const v8bf*)(vb);
        v8bf v1 = *(const v8bf*)(vb + 8);
#pragma unroll
        for (int e = 0; e < 8; ++e) {
            pacc[e] += a * (float)v0[e];
            pacc[8 + e] += a * (float)v1[e];
        }
    }
#pragma unroll
    for (int q = 0; q < 4; ++q) {
        int phys = lane * 4 + (q ^ (lane & 3));
        *(float4*)&sAcc[wv * 1024 + phys * 4] =
            make_float4(pacc[q * 4], pacc[q * 4 + 1], pacc[q * 4 + 2], pacc[q * 4 + 3]);
    }
    __syncthreads();

    const int lr = tid >> 2, qr = tid & 3;
    const int phys = lr * 4 + (qr ^ (lr & 3));
    float4 p0 = *(const float4*)&sAcc[0 * 1024 + phys * 4];
    float4 p1 = *(const float4*)&sAcc[1 * 1024 + phys * 4];
    float4 p2 = *(const float4*)&sAcc[2 * 1024 + phys * 4];
    float4 p3 = *(const float4*)&sAcc[3 * 1024 + phys * 4];
    v4bf gv = *(const v4bf*)(qkvg + (size_t)t * RS + 3 * DIM + tid * 4);
    v4bf ov;
    ov[0] = (bf16)((p0.x + p1.x + p2.x + p3.x) * inv * (float)gv[0]);
    ov[1] = (bf16)((p0.y + p1.y + p2.y + p3.y) * inv * (float)gv[1]);
    ov[2] = (bf16)((p0.z + p1.z + p2.z + p3.z) * inv * (float)gv[2]);
    ov[3] = (bf16)((p0.w + p1.w + p2.w + p3.w) * inv * (float)gv[3]);
    *(v4bf*)(attgb + (size_t)t * DIM + tid * 4) = ov;
}

// ---------- bf16 MFMA GEMM, NBUF-deep pipeline, counted vmcnt, XOR-swizzled LDS ----------
// SWZ=1: bijective n-major XCD chunking (bounds per-XCD B working set)
// EPI: 3 = residual f32; 5 = qkv+gate; 6 = interleaved ffn gate/up via LDS exchange
template<int BM, int BN, int NTHR, int NBUF, int EPI, int SWZ>
__global__ __launch_bounds__(NTHR) void gemm_kernel(
    const bf16* __restrict__ A, const bf16* __restrict__ Bt,
    int M, int N, int K,
    float* __restrict__ outf, bf16* __restrict__ outb,
    const float* __restrict__ e1, const float* __restrict__ bias)
{
    constexpr int WAVES = NTHR / 64;
    constexpr int WCOLS = WAVES / 2;
    constexpr int WME = BM / 2;
    constexpr int WNE = BN / WCOLS;
    constexpr int MI = WME / 16;
    constexpr int NJ = WNE / 16;
    constexpr int CH_A = BM * 4, CH_B = BN * 4;
    constexpr int LPT = (CH_A + CH_B) / NTHR;
    constexpr int STAGE_BYTES = NBUF * (BM + BN) * 32 * 2;
    constexpr int EPI_BYTES = (EPI == 6) ? BM * 66 * 4 : 0;
    constexpr int SMEM_BYTES = STAGE_BYTES > EPI_BYTES ? STAGE_BYTES : EPI_BYTES;
    __shared__ __align__(16) char smem[SMEM_BYTES];
    bf16* AsB = (bf16*)smem;
    bf16* BsB = (bf16*)(smem + NBUF * BM * 32 * 2);

    const int tid = threadIdx.x;
    int m0, n0;
    if constexpr (SWZ) {
        const int nx = gridDim.x, ny = gridDim.y;
        const int w = blockIdx.y * nx + blockIdx.x;
        const int total = nx * ny, q = total >> 3, r = total & 7;
        const int xcd = w & 7, i = w >> 3;
        const int f = xcd * q + (xcd < r ? xcd : r) + i;
        m0 = (f % ny) * BM;
        n0 = (f / ny) * BN;
    } else {
        m0 = blockIdx.y * BM;
        n0 = blockIdx.x * BN;
    }
    const int lane = tid & 63, wave = tid >> 6;
    const int wr = wave / WCOLS, wc = wave % WCOLS;
    const int wm = wr * WME, wn = wc * WNE;
    const int lrow = lane & 15, l16 = lane >> 4;

    const bf16* gptr[LPT];
    int lo[LPT];
    bool pa[LPT];
#pragma unroll
    for (int i = 0; i < LPT; ++i) {
        int c = tid + i * NTHR;
        bool inA = c < CH_A;
        int cc = inA ? c : c - CH_A;
        int r = cc >> 2, q = cc & 3;
        int gq = (q ^ ((r >> 1) & 3)) * 8;
        gptr[i] = inA ? A + (size_t)(m0 + r) * K + gq
                      : Bt + (size_t)(n0 + r) * K + gq;
        lo[i] = r * 32 + q * 8;
        pa[i] = inA;
    }

    auto STAGE = [&](int b, int kt) {
        const int ko = kt * 32;
#pragma unroll
        for (int i = 0; i < LPT; ++i) {
            bf16* dst = (pa[i] ? AsB + b * BM * 32 : BsB + b * BN * 32) + lo[i];
            GLL(gptr[i] + ko, dst);
        }
    };

    v4f acc[MI][NJ] = {};
    auto COMPUTE = [&](int b) {
        v8bf af[MI], bfr[NJ];
#pragma unroll
        for (int i = 0; i < MI; ++i) {
            int r = wm + i * 16 + lrow;
            af[i] = *(v8bf*)&AsB[b * BM * 32 + r * 32 + ((l16 ^ ((r >> 1) & 3)) * 8)];
        }
#pragma unroll
        for (int j = 0; j < NJ; ++j) {
            int r = wn + j * 16 + lrow;
            bfr[j] = *(v8bf*)&BsB[b * BN * 32 + r * 32 + ((l16 ^ ((r >> 1) & 3)) * 8)];
        }
        __builtin_amdgcn_s_setprio(1);
#pragma unroll
        for (int i = 0; i < MI; ++i)
#pragma unroll
            for (int j = 0; j < NJ; ++j)
                acc[i][j] = __builtin_amdgcn_mfma_f32_16x16x32_bf16(af[i], bfr[j], acc[i][j], 0, 0, 0);
        __builtin_amdgcn_s_setprio(0);
    };

    const int NT = K >> 5;
    constexpr int PIPE = NBUF >= 3 ? NBUF : NBUF;
#pragma unroll
    for (int i = 0; i < PIPE; ++i) STAGE(i % NBUF, i);
    for (int t = 0; t < NT - (PIPE - 1); ++t) {
        WAITV((PIPE - 1) * LPT);
        __builtin_amdgcn_s_barrier();
        __builtin_amdgcn_sched_barrier(0);
        COMPUTE(t % NBUF);
        __builtin_amdgcn_sched_barrier(0);
        __builtin_amdgcn_s_barrier();
        if (t + PIPE < NT) STAGE(t % NBUF, t + PIPE);
    }
#pragma unroll
    for (int e = PIPE - 1; e >= 1; --e) {
        const int t = NT - e;
        WAITV((e - 1) * LPT);
        __builtin_amdgcn_s_barrier();
        __builtin_amdgcn_sched_barrier(0);
        COMPUTE(t % NBUF);
        __builtin_amdgcn_sched_barrier(0);
        __builtin_amdgcn_s_barrier();
    }

    if constexpr (EPI == 6) {
        float* eps = (float*)smem;
        const bool isGate = (wn < 64);
        if (isGate) {
#pragma unroll
            for (int i = 0; i < MI; ++i)
#pragma unroll
                for (int j = 0; j < NJ; ++j)
#pragma unroll
                    for (int r = 0; r < 4; ++r) {
                        int rowL = wm + i * 16 + l16 * 4 + r;
                        int colL = wn + j * 16 + lrow;
                        eps[rowL * 66 + colL] = acc[i][j][r];
                    }
        }
        asm volatile("s_waitcnt lgkmcnt(0)" ::: "memory");
        __builtin_amdgcn_s_barrier();
        if (!isGate) {
            const int halfN = N >> 1;
#pragma unroll
            for (int i = 0; i < MI; ++i)
#pragma unroll
                for (int j = 0; j < NJ; ++j)
#pragma unroll
                    for (int r = 0; r < 4; ++r) {
                        int rowL = wm + i * 16 + l16 * 4 + r;
                        int colU = wn - 64 + j * 16 + lrow;
                        float g = eps[rowL * 66 + colU];
                        float sil = g / (1.0f + __expf(-g));
                        float u = acc[i][j][r];
                        outb[(size_t)(m0 + rowL) * halfN + (n0 >> 1) + colU] = (bf16)(sil * u);
                    }
        }
        return;
    }

#pragma unroll
    for (int i = 0; i < MI; ++i)
#pragma unroll
        for (int j = 0; j < NJ; ++j)
#pragma unroll
            for (int r = 0; r < 4; ++r) {
                int row = m0 + wm + i * 16 + l16 * 4 + r;
                int col = n0 + wn + j * 16 + lrow;
                size_t idx = (size_t)row * N + col;
                float v = acc[i][j][r];
                if constexpr (EPI == 3) {
                    outf[idx] = e1[idx] + v;
                } else if constexpr (EPI == 5) {
                    if (col >= 3 * DIM) {
                        float g = 1.0f / (1.0f + __expf(-(v + bias[col - 3 * DIM])));
                        outb[idx] = (bf16)g;
                    } else {
                        outb[idx] = (bf16)v;
                    }
                }
            }
}

extern "C" void kernel_launch(void* const* d_in, const int* in_sizes, int n_in,
                              void* d_out, int out_size, void* d_ws, size_t ws_size,
                              hipStream_t stream)
{
    const float* x        = (const float*)d_in[0];
    const float* n1s      = (const float*)d_in[1];
    const float* n2s      = (const float*)d_in[2];
    const float* w_qkv    = (const float*)d_in[3];
    const float* w_out    = (const float*)d_in[4];
    const float* w_gate   = (const float*)d_in[5];
    const float* b_gate   = (const float*)d_in[6];
    const float* pos_bias = (const float*)d_in[7];
    const float* w_ffng   = (const float*)d_in[8];
    const float* w_ffnu   = (const float*)d_in[9];
    const float* w_ffnd   = (const float*)d_in[10];
    const int* offsets    = (const int*)d_in[11];
    float* out = (float*)d_out;

    char* ws = (char*)d_ws;
    size_t cur = 0;
    auto alloc = [&](size_t bytes) -> void* {
        void* p = ws + cur;
        cur += (bytes + 255) & ~(size_t)255;
        return p;
    };
    bf16*  xnb    = (bf16*)alloc((size_t)N_TOK * DIM * 2);
    bf16*  qkvgb  = (bf16*)alloc((size_t)N_TOK * 4 * DIM * 2);
    bf16*  attgb  = (bf16*)alloc((size_t)N_TOK * DIM * 2);
    float* x1     = (float*)alloc((size_t)N_TOK * DIM * 4);
    bf16*  xn2b   = (bf16*)alloc((size_t)N_TOK * DIM * 2);
    bf16*  hb     = (bf16*)alloc((size_t)N_TOK * FFN_DIM * 2);
    bf16*  wqkvgT = (bf16*)alloc((size_t)4 * DIM * DIM * 2);
    bf16*  woutT  = (bf16*)alloc((size_t)DIM * DIM * 2);
    bf16*  wcatT  = (bf16*)alloc((size_t)2 * FFN_DIM * DIM * 2);
    bf16*  wffndT = (bf16*)alloc((size_t)FFN_DIM * DIM * 2);

    transpose_all_kernel<<<13568, dim3(32, 8), 0, stream>>>(
        w_qkv, w_gate, w_out, w_ffng, w_ffnu, w_ffnd,
        wqkvgT, woutT, wcatT, wffndT);

    rmsnorm_kernel<<<N_TOK, 256, 0, stream>>>(x, n1s, xnb);
    // fused qkv + gate: 128x128, 512 thr, NBUF=3, XCD swizzle
    gemm_kernel<128, 128, 512, 3, 5, 1><<<dim3(32, 16), 512, 0, stream>>>(
        xnb, wqkvgT, N_TOK, 4 * DIM, DIM, nullptr, qkvgb, nullptr, b_gate);
    attn_kernel<<<dim3(N_TOK), 256, 0, stream>>>(qkvgb, offsets, pos_bias, attgb);
    // x1 = x + attg @ w_out  (64x64, NBUF=4)
    gemm_kernel<64, 64, 256, 4, 3, 0><<<dim3(16, 32), 256, 0, stream>>>(
        attgb, woutT, N_TOK, DIM, DIM, x1, nullptr, x, nullptr);
    rmsnorm_kernel<<<N_TOK, 256, 0, stream>>>(x1, n2s, xn2b);
    // fused ffn gate|up interleaved: 128x128, 512 thr, NBUF=3, XCD swizzle
    gemm_kernel<128, 128, 512, 3, 6, 1><<<dim3(44, 16), 512, 0, stream>>>(
        xn2b, wcatT, N_TOK, 2 * FFN_DIM, DIM, nullptr, hb, nullptr, nullptr);
    // out = x1 + hb @ w_ffn_down  (64x64, K=2816, NBUF=4, XCD swizzle)
    gemm_kernel<64, 64, 256, 4, 3, 1><<<dim3(16, 32), 256, 0, stream>>>(
        hb, wffndT, N_TOK, DIM, FFN_DIM, out, nullptr, x1, nullptr);
}

// Round 8
// 153.083 us; speedup vs baseline: 1.0912x; 1.0262x over previous
//
#include <hip/hip_runtime.h>
#include <hip/hip_bf16.h>
#include <math.h>

typedef __bf16 bf16;
typedef __bf16 v8bf __attribute__((ext_vector_type(8)));
typedef __bf16 v4bf __attribute__((ext_vector_type(4)));
typedef float v4f __attribute__((ext_vector_type(4)));

#define N_TOK 2048
#define DIM 1024
#define NH 16
#define FFN_DIM 2816

#define GLL(g, l) __builtin_amdgcn_global_load_lds(                         \
    (const __attribute__((address_space(1))) uint32_t*)(g),                 \
    (__attribute__((address_space(3))) uint32_t*)(l), 16, 0, 0)

#define WAITV(n) do {                                                        \
    switch (n) {                                                             \
    case 0: asm volatile("s_waitcnt vmcnt(0)" ::: "memory"); break;          \
    case 2: asm volatile("s_waitcnt vmcnt(2)" ::: "memory"); break;          \
    case 4: asm volatile("s_waitcnt vmcnt(4)" ::: "memory"); break;          \
    case 6: asm volatile("s_waitcnt vmcnt(6)" ::: "memory"); break;          \
    case 8: asm volatile("s_waitcnt vmcnt(8)" ::: "memory"); break;          \
    default: asm volatile("s_waitcnt vmcnt(0)" ::: "memory"); break; }       \
} while (0)

// ---------- all weight transposes+cvt in ONE launch ----------
__global__ __launch_bounds__(256) void transpose_all_kernel(
    const float* __restrict__ w_qkv, const float* __restrict__ w_gate,
    const float* __restrict__ w_out, const float* __restrict__ w_ffng,
    const float* __restrict__ w_ffnu, const float* __restrict__ w_ffnd,
    bf16* __restrict__ wqkvgT, bf16* __restrict__ woutT,
    bf16* __restrict__ wcatT, bf16* __restrict__ wffndT)
{
    int bid = blockIdx.x;
    const float* W; bf16* D; int Kd, Nc, nb, kb, dstbase;
    if (bid < 3072) {
        W = w_qkv; D = wqkvgT; Kd = 1024; Nc = 3072;
        nb = (bid % 96) * 32; kb = (bid / 96) * 32; dstbase = nb;
    } else if (bid < 4096) { int b = bid - 3072;
        W = w_gate; D = wqkvgT; Kd = 1024; Nc = 1024;
        nb = (b % 32) * 32; kb = (b / 32) * 32; dstbase = 3072 + nb;
    } else if (bid < 5120) { int b = bid - 4096;
        W = w_out; D = woutT; Kd = 1024; Nc = 1024;
        nb = (b % 32) * 32; kb = (b / 32) * 32; dstbase = nb;
    } else if (bid < 7936) { int b = bid - 5120;
        W = w_ffng; D = wcatT; Kd = 1024; Nc = 2816;
        nb = (b % 88) * 32; kb = (b / 88) * 32;
        dstbase = (nb >> 6) * 128 + (nb & 63);
    } else if (bid < 10752) { int b = bid - 7936;
        W = w_ffnu; D = wcatT; Kd = 1024; Nc = 2816;
        nb = (b % 88) * 32; kb = (b / 88) * 32;
        dstbase = (nb >> 6) * 128 + 64 + (nb & 63);
    } else { int b = bid - 10752;
        W = w_ffnd; D = wffndT; Kd = 2816; Nc = 1024;
        nb = (b % 32) * 32; kb = (b / 32) * 32; dstbase = nb;
    }
    __shared__ float tile[32][33];
    int tx = threadIdx.x, ty = threadIdx.y;
#pragma unroll
    for (int r = 0; r < 4; ++r)
        tile[ty + r * 8][tx] = W[(size_t)(kb + ty + r * 8) * Nc + nb + tx];
    __syncthreads();
#pragma unroll
    for (int r = 0; r < 4; ++r)
        D[(size_t)(dstbase + ty + r * 8) * Kd + kb + tx] = (bf16)tile[tx][ty + r * 8];
}

// ---------- RMSNorm (f32 in -> bf16 out) ----------
__global__ __launch_bounds__(256) void rmsnorm_kernel(
    const float* __restrict__ x, const float* __restrict__ scale, bf16* __restrict__ out)
{
    int row = blockIdx.x, tid = threadIdx.x;
    float4 v = ((const float4*)(x + (size_t)row * DIM))[tid];
    float ss = v.x * v.x + v.y * v.y + v.z * v.z + v.w * v.w;
#pragma unroll
    for (int off = 32; off > 0; off >>= 1) ss += __shfl_down(ss, off);
    __shared__ float ps[4];
    if ((tid & 63) == 0) ps[tid >> 6] = ss;
    __syncthreads();
    float tot = ps[0] + ps[1] + ps[2] + ps[3];
    float inv = rsqrtf(tot * (1.0f / DIM) + 1e-6f);
    float4 s = ((const float4*)scale)[tid];
    union { bf16 b[4]; uint2 u; } p;
    p.b[0] = (bf16)(v.x * inv * s.x);
    p.b[1] = (bf16)(v.y * inv * s.y);
    p.b[2] = (bf16)(v.z * inv * s.z);
    p.b[3] = (bf16)(v.w * inv * s.w);
    ((uint2*)(out + (size_t)row * DIM))[tid] = p.u;
}

// ---------- gathered-offset attention + gate multiply ----------
__global__ __launch_bounds__(256) void attn_kernel(
    const bf16* __restrict__ qkvg, const int* __restrict__ offs,
    const float* __restrict__ pos_bias, bf16* __restrict__ attgb)
{
    constexpr int O = 44;
    const int t = blockIdx.x, tid = threadIdx.x;
    const int wv = tid >> 6, lane = tid & 63;
    const int h1 = lane >> 2, l4 = lane & 3;
    const size_t RS = 4 * DIM;
    __shared__ float sS[O][17];
    __shared__ float sPB[O * 16];
    __shared__ int so[O];
    __shared__ float sAcc[4 * 1024];
    if (tid < O) so[tid] = offs[tid];
    for (int i = tid; i < O * 16; i += 256) sPB[i] = pos_bias[i];
    __syncthreads();

    // ----- phase 1: scores -----
    const bf16* qbase = qkvg + (size_t)t * RS + h1 * 64;
    v8bf q0v = *(const v8bf*)(qbase + l4 * 8);
    v8bf q1v = *(const v8bf*)(qbase + 32 + l4 * 8);
    float qa[16];
#pragma unroll
    for (int e = 0; e < 8; ++e) {
        qa[e] = (float)q0v[e] * 0.125f;
        qa[8 + e] = (float)q1v[e] * 0.125f;
    }

#pragma unroll 4
    for (int it = 0; it < 11; ++it) {
        const int o = it * 4 + wv;
        const int src = t - so[o];
        const int srcc = src < 0 ? 0 : src;
        const bf16* kbase = qkvg + (size_t)srcc * RS + DIM + h1 * 64;
        v8bf k0 = *(const v8bf*)(kbase + l4 * 8);
        v8bf k1 = *(const v8bf*)(kbase + 32 + l4 * 8);
        float p = 0.f;
#pragma unroll
        for (int e = 0; e < 8; ++e) p += qa[e] * (float)k0[e];
#pragma unroll
        for (int e = 0; e < 8; ++e) p += qa[8 + e] * (float)k1[e];
        p += __shfl_xor(p, 1);
        p += __shfl_xor(p, 2);
        float s = (src >= 0) ? p + sPB[o * NH + h1] : -INFINITY;
        if (l4 == 0) sS[o][h1] = s;
    }
    __syncthreads();

    // ----- phase 2: per-head softmax stats -----
    const int h = tid >> 4, j16 = tid & 15;
    float mx = -INFINITY;
#pragma unroll
    for (int o = j16; o < O; o += 16) mx = fmaxf(mx, sS[o][h]);
    mx = fmaxf(mx, __shfl_xor(mx, 1));
    mx = fmaxf(mx, __shfl_xor(mx, 2));
    mx = fmaxf(mx, __shfl_xor(mx, 4));
    mx = fmaxf(mx, __shfl_xor(mx, 8));
    float sum = 0.f;
#pragma unroll
    for (int o = j16; o < O; o += 16) {
        float e = __expf(sS[o][h] - mx);
        sS[o][h] = e;
        sum += e;
    }
    sum += __shfl_xor(sum, 1);
    sum += __shfl_xor(sum, 2);
    sum += __shfl_xor(sum, 4);
    sum += __shfl_xor(sum, 8);
    float inv = 1.0f / sum;
    __syncthreads();

    // ----- phase 3: PV, offsets split across waves; lane owns 16 dims -----
    const int h2 = lane >> 2;
    const int dbase = lane * 16;
    float pacc[16] = {};
#pragma unroll 4
    for (int it = 0; it < 11; ++it) {
        int o = it * 4 + wv;
        int src = t - so[o];
        int srcc = src < 0 ? 0 : src;
        float a = sS[o][h2];
        const bf16* vb = qkvg + (size_t)srcc * RS + 2 * DIM + dbase;
        v8bf v0 = *(const v8bf*)(vb);
        v8bf v1 = *(const v8bf*)(vb + 8);
#pragma unroll
        for (int e = 0; e < 8; ++e) {
            pacc[e] += a * (float)v0[e];
            pacc[8 + e] += a * (float)v1[e];
        }
    }
#pragma unroll
    for (int q = 0; q < 4; ++q) {
        int phys = lane * 4 + (q ^ (lane & 3));
        *(float4*)&sAcc[wv * 1024 + phys * 4] =
            make_float4(pacc[q * 4], pacc[q * 4 + 1], pacc[q * 4 + 2], pacc[q * 4 + 3]);
    }
    __syncthreads();

    const int lr = tid >> 2, qr = tid & 3;
    const int phys = lr * 4 + (qr ^ (lr & 3));
    float4 p0 = *(const float4*)&sAcc[0 * 1024 + phys * 4];
    float4 p1 = *(const float4*)&sAcc[1 * 1024 + phys * 4];
    float4 p2 = *(const float4*)&sAcc[2 * 1024 + phys * 4];
    float4 p3 = *(const float4*)&sAcc[3 * 1024 + phys * 4];
    v4bf gv = *(const v4bf*)(qkvg + (size_t)t * RS + 3 * DIM + tid * 4);
    v4bf ov;
    ov[0] = (bf16)((p0.x + p1.x + p2.x + p3.x) * inv * (float)gv[0]);
    ov[1] = (bf16)((p0.y + p1.y + p2.y + p3.y) * inv * (float)gv[1]);
    ov[2] = (bf16)((p0.z + p1.z + p2.z + p3.z) * inv * (float)gv[2]);
    ov[3] = (bf16)((p0.w + p1.w + p2.w + p3.w) * inv * (float)gv[3]);
    *(v4bf*)(attgb + (size_t)t * DIM + tid * 4) = ov;
}

// ---------- bf16 MFMA GEMM: single-barrier pipelined loop, counted vmcnt ----------
// Per iter t: vmcnt(counted) -> s_barrier -> ds_read frags(buf t%NBUF)
//             -> issue STAGE(t+NBUF-1 into buf (t-1)%NBUF) -> MFMA.
// Stage target buffer was consumed at iter t-1 by all waves (they passed this
// barrier), and each wave's ds_reads completed before its own barrier arrival
// (compiler lgkmcnt before MFMA) -> race-free with ONE barrier per iteration.
// EPI: 3 = residual f32; 5 = qkv+gate; 6 = interleaved ffn gate/up via LDS exchange
template<int BM, int BN, int NTHR, int NBUF, int EPI>
__global__ __launch_bounds__(NTHR) void gemm_kernel(
    const bf16* __restrict__ A, const bf16* __restrict__ Bt,
    int M, int N, int K,
    float* __restrict__ outf, bf16* __restrict__ outb,
    const float* __restrict__ e1, const float* __restrict__ bias)
{
    constexpr int WAVES = NTHR / 64;
    constexpr int WCOLS = WAVES / 2;
    constexpr int WME = BM / 2;
    constexpr int WNE = BN / WCOLS;
    constexpr int MI = WME / 16;
    constexpr int NJ = WNE / 16;
    constexpr int CH_A = BM * 4, CH_B = BN * 4;
    constexpr int LPT = (CH_A + CH_B) / NTHR;
    constexpr int STAGE_BYTES = NBUF * (BM + BN) * 32 * 2;
    constexpr int EPI_BYTES = (EPI == 6) ? BM * 66 * 4 : 0;
    constexpr int SMEM_BYTES = STAGE_BYTES > EPI_BYTES ? STAGE_BYTES : EPI_BYTES;
    __shared__ __align__(16) char smem[SMEM_BYTES];
    bf16* AsB = (bf16*)smem;
    bf16* BsB = (bf16*)(smem + NBUF * BM * 32 * 2);

    const int tid = threadIdx.x;
    const int m0 = blockIdx.y * BM, n0 = blockIdx.x * BN;
    const int lane = tid & 63, wave = tid >> 6;
    const int wr = wave / WCOLS, wc = wave % WCOLS;
    const int wm = wr * WME, wn = wc * WNE;
    const int lrow = lane & 15, l16 = lane >> 4;

    const bf16* gptr[LPT];
    int lo[LPT];
    bool pa[LPT];
#pragma unroll
    for (int i = 0; i < LPT; ++i) {
        int c = tid + i * NTHR;
        bool inA = c < CH_A;
        int cc = inA ? c : c - CH_A;
        int r = cc >> 2, q = cc & 3;
        int gq = (q ^ ((r >> 1) & 3)) * 8;
        gptr[i] = inA ? A + (size_t)(m0 + r) * K + gq
                      : Bt + (size_t)(n0 + r) * K + gq;
        lo[i] = r * 32 + q * 8;
        pa[i] = inA;
    }

    auto STAGE = [&](int b, int kt) {
        const int ko = kt * 32;
#pragma unroll
        for (int i = 0; i < LPT; ++i) {
            bf16* dst = (pa[i] ? AsB + b * BM * 32 : BsB + b * BN * 32) + lo[i];
            GLL(gptr[i] + ko, dst);
        }
    };

    v4f acc[MI][NJ] = {};
    const int NT = K >> 5;
#pragma unroll
    for (int i = 0; i < NBUF - 1; ++i) STAGE(i, i);

    for (int t = 0; t < NT; ++t) {
        const int rem = NT - 1 - t;
        const int wv_n = (rem < NBUF - 2 ? rem : NBUF - 2) * LPT;
        WAITV(wv_n);
        __builtin_amdgcn_s_barrier();
        __builtin_amdgcn_sched_barrier(0);
        const int b = t % NBUF;
        v8bf af[MI], bfr[NJ];
#pragma unroll
        for (int i = 0; i < MI; ++i) {
            int r = wm + i * 16 + lrow;
            af[i] = *(v8bf*)&AsB[b * BM * 32 + r * 32 + ((l16 ^ ((r >> 1) & 3)) * 8)];
        }
#pragma unroll
        for (int j = 0; j < NJ; ++j) {
            int r = wn + j * 16 + lrow;
            bfr[j] = *(v8bf*)&BsB[b * BN * 32 + r * 32 + ((l16 ^ ((r >> 1) & 3)) * 8)];
        }
        if (t + NBUF - 1 < NT) STAGE((t + NBUF - 1) % NBUF, t + NBUF - 1);
        __builtin_amdgcn_s_setprio(1);
#pragma unroll
        for (int i = 0; i < MI; ++i)
#pragma unroll
            for (int j = 0; j < NJ; ++j)
                acc[i][j] = __builtin_amdgcn_mfma_f32_16x16x32_bf16(af[i], bfr[j], acc[i][j], 0, 0, 0);
        __builtin_amdgcn_s_setprio(0);
    }

    if constexpr (EPI == 6) {
        float* eps = (float*)smem;
        const bool isGate = (wn < 64);
        asm volatile("s_waitcnt lgkmcnt(0)" ::: "memory");
        __builtin_amdgcn_s_barrier();   // all waves done with staging buffers
        if (isGate) {
#pragma unroll
            for (int i = 0; i < MI; ++i)
#pragma unroll
                for (int j = 0; j < NJ; ++j)
#pragma unroll
                    for (int r = 0; r < 4; ++r) {
                        int rowL = wm + i * 16 + l16 * 4 + r;
                        int colL = wn + j * 16 + lrow;
                        eps[rowL * 66 + colL] = acc[i][j][r];
                    }
        }
        asm volatile("s_waitcnt lgkmcnt(0)" ::: "memory");
        __builtin_amdgcn_s_barrier();
        if (!isGate) {
            const int halfN = N >> 1;
#pragma unroll
            for (int i = 0; i < MI; ++i)
#pragma unroll
                for (int j = 0; j < NJ; ++j)
#pragma unroll
                    for (int r = 0; r < 4; ++r) {
                        int rowL = wm + i * 16 + l16 * 4 + r;
                        int colU = wn - 64 + j * 16 + lrow;
                        float g = eps[rowL * 66 + colU];
                        float sil = g / (1.0f + __expf(-g));
                        float u = acc[i][j][r];
                        outb[(size_t)(m0 + rowL) * halfN + (n0 >> 1) + colU] = (bf16)(sil * u);
                    }
        }
        return;
    }

#pragma unroll
    for (int i = 0; i < MI; ++i)
#pragma unroll
        for (int j = 0; j < NJ; ++j)
#pragma unroll
            for (int r = 0; r < 4; ++r) {
                int row = m0 + wm + i * 16 + l16 * 4 + r;
                int col = n0 + wn + j * 16 + lrow;
                size_t idx = (size_t)row * N + col;
                float v = acc[i][j][r];
                if constexpr (EPI == 3) {
                    outf[idx] = e1[idx] + v;
                } else if constexpr (EPI == 5) {
                    if (col >= 3 * DIM) {
                        float g = 1.0f / (1.0f + __expf(-(v + bias[col - 3 * DIM])));
                        outb[idx] = (bf16)g;
                    } else {
                        outb[idx] = (bf16)v;
                    }
                }
            }
}

extern "C" void kernel_launch(void* const* d_in, const int* in_sizes, int n_in,
                              void* d_out, int out_size, void* d_ws, size_t ws_size,
                              hipStream_t stream)
{
    const float* x        = (const float*)d_in[0];
    const float* n1s      = (const float*)d_in[1];
    const float* n2s      = (const float*)d_in[2];
    const float* w_qkv    = (const float*)d_in[3];
    const float* w_out    = (const float*)d_in[4];
    const float* w_gate   = (const float*)d_in[5];
    const float* b_gate   = (const float*)d_in[6];
    const float* pos_bias = (const float*)d_in[7];
    const float* w_ffng   = (const float*)d_in[8];
    const float* w_ffnu   = (const float*)d_in[9];
    const float* w_ffnd   = (const float*)d_in[10];
    const int* offsets    = (const int*)d_in[11];
    float* out = (float*)d_out;

    char* ws = (char*)d_ws;
    size_t cur = 0;
    auto alloc = [&](size_t bytes) -> void* {
        void* p = ws + cur;
        cur += (bytes + 255) & ~(size_t)255;
        return p;
    };
    bf16*  xnb    = (bf16*)alloc((size_t)N_TOK * DIM * 2);
    bf16*  qkvgb  = (bf16*)alloc((size_t)N_TOK * 4 * DIM * 2);
    bf16*  attgb  = (bf16*)alloc((size_t)N_TOK * DIM * 2);
    float* x1     = (float*)alloc((size_t)N_TOK * DIM * 4);
    bf16*  xn2b   = (bf16*)alloc((size_t)N_TOK * DIM * 2);
    bf16*  hb     = (bf16*)alloc((size_t)N_TOK * FFN_DIM * 2);
    bf16*  wqkvgT = (bf16*)alloc((size_t)4 * DIM * DIM * 2);
    bf16*  woutT  = (bf16*)alloc((size_t)DIM * DIM * 2);
    bf16*  wcatT  = (bf16*)alloc((size_t)2 * FFN_DIM * DIM * 2);
    bf16*  wffndT = (bf16*)alloc((size_t)FFN_DIM * DIM * 2);

    transpose_all_kernel<<<13568, dim3(32, 8), 0, stream>>>(
        w_qkv, w_gate, w_out, w_ffng, w_ffnu, w_ffnd,
        wqkvgT, woutT, wcatT, wffndT);

    rmsnorm_kernel<<<N_TOK, 256, 0, stream>>>(x, n1s, xnb);
    // fused qkv + gate: 128x128, 512 thr, NBUF=3, single-barrier pipeline
    gemm_kernel<128, 128, 512, 3, 5><<<dim3(32, 16), 512, 0, stream>>>(
        xnb, wqkvgT, N_TOK, 4 * DIM, DIM, nullptr, qkvgb, nullptr, b_gate);
    attn_kernel<<<dim3(N_TOK), 256, 0, stream>>>(qkvgb, offsets, pos_bias, attgb);
    // x1 = x + attg @ w_out  (64x64, NBUF=4)
    gemm_kernel<64, 64, 256, 4, 3><<<dim3(16, 32), 256, 0, stream>>>(
        attgb, woutT, N_TOK, DIM, DIM, x1, nullptr, x, nullptr);
    rmsnorm_kernel<<<N_TOK, 256, 0, stream>>>(x1, n2s, xn2b);
    // fused ffn gate|up interleaved: 128x128, 512 thr, NBUF=3
    gemm_kernel<128, 128, 512, 3, 6><<<dim3(44, 16), 512, 0, stream>>>(
        xn2b, wcatT, N_TOK, 2 * FFN_DIM, DIM, nullptr, hb, nullptr, nullptr);
    // out = x1 + hb @ w_ffn_down  (64x64, K=2816, NBUF=4)
    gemm_kernel<64, 64, 256, 4, 3><<<dim3(16, 32), 256, 0, stream>>>(
        hb, wffndT, N_TOK, DIM, FFN_DIM, out, nullptr, x1, nullptr);
}